// Round 1
// baseline (2430.161 us; speedup 1.0000x reference)
//
#include <hip/hip_runtime.h>

// ---------------------------------------------------------------------------
// MultiHeadSA, fp32 baseline with algebraic restructure:
//   M_h = Wk_h^T Wq_h / 16          [256x256]   (q-side bias terms cancel in
//   u_h = Wk_h^T bq_h / 16          [256]        softmax over the key axis)
//   U_h = Wo_h Wv_h                 [256x256]
//   b'  = bo + sum_h Wo_h bv_h      [256]       (softmax cols sum to 1)
//   logits_h = X^T (M_h X) + u_h^T X (per-k) + pos_h ; w = softmax_k
//   Y_h = X w_h ; out = U_all Y + b'
// ---------------------------------------------------------------------------

constexpr int NB = 8, NH = 8, DD = 256, PP = 1024;
constexpr int QT = 64;   // q-tile per flash block
constexpr int KT = 64;   // k-tile per iteration

// workspace offsets (floats)
constexpr size_t OFF_M  = 0;         // [8][256][256]
constexpr size_t OFF_U  = 524288;    // [256][2048]  (U_all[o][h*256+i])
constexpr size_t OFF_u  = 1048576;   // [8][256]
constexpr size_t OFF_bp = 1050624;   // [256]
constexpr size_t OFF_ck = 1050880;   // [8][8][1024]
constexpr size_t OFF_Y  = 1116416;   // [8][2048][1024]

// flash kernel LDS layout (floats)
constexpr int L_TQ   = 0;      // Tq[256][64]  (phase B) / Mt[32][260] (phase A)
constexpr int L_XQ   = 16384;  // Xq[256][64]  (phase A) / Xc[64][260] (phase B)
constexpr int L_PL   = 33024;  // Pl[64][64]
constexpr int L_CK   = 37120;  // cks[64]
constexpr int L_RED  = 37184;  // red[8][64]
constexpr int L_MNEW = 37696;
constexpr int L_SCL  = 37760;
constexpr int L_MRUN = 37824;
constexpr int L_LRUN = 37888;
constexpr int L_TOTAL = 37952; // floats -> 151808 bytes (<160 KiB)

// ---------------- M_h and U_h precompute ----------------
// grid (4 row-tiles, 8 heads, 2 modes), 256 threads
__global__ __launch_bounds__(256, 1) void msa_mu(
    const float* __restrict__ Wk, const float* __restrict__ Wq,
    const float* __restrict__ Wo, const float* __restrict__ Wv,
    float* __restrict__ M, float* __restrict__ Uall) {
  __shared__ float lds[64 * 65];
  const int t = threadIdx.x;
  const int i0 = blockIdx.x * 64;   // output-row tile (i for M, o for U)
  const int h = blockIdx.y;
  const int mode = blockIdx.z;      // 0: M, 1: U
  const int j0 = (t & 127) * 2;
  const int ihalf = t >> 7;
  float acc0[32], acc1[32];
#pragma unroll
  for (int r = 0; r < 32; ++r) { acc0[r] = 0.f; acc1[r] = 0.f; }
  const float* __restrict__ W2 = (mode == 0) ? Wq : Wv;
  for (int dhc = 0; dhc < 256; dhc += 64) {
    __syncthreads();
    if (mode == 0) {
#pragma unroll
      for (int s = 0; s < 16; ++s) {
        int f = t + s * 256;
        int dh = f >> 6, ii = f & 63;
        lds[dh * 65 + ii] = Wk[(h * 256 + dhc + dh) * 256 + i0 + ii];
      }
    } else {
#pragma unroll
      for (int s = 0; s < 16; ++s) {
        int f = t + s * 256;
        int oo = f >> 6, dh = f & 63;
        lds[dh * 65 + oo] = Wo[(i0 + oo) * 2048 + h * 256 + dhc + dh];
      }
    }
    __syncthreads();
    for (int dl = 0; dl < 64; ++dl) {
      float2 w = *reinterpret_cast<const float2*>(&W2[(h * 256 + dhc + dl) * 256 + j0]);
#pragma unroll
      for (int r = 0; r < 32; ++r) {
        float x = lds[dl * 65 + ihalf * 32 + r];
        acc0[r] = fmaf(x, w.x, acc0[r]);
        acc1[r] = fmaf(x, w.y, acc1[r]);
      }
    }
  }
  if (mode == 0) {
#pragma unroll
    for (int r = 0; r < 32; ++r) {
      int i = i0 + ihalf * 32 + r;
      float2 v = make_float2(acc0[r] * 0.0625f, acc1[r] * 0.0625f);
      *reinterpret_cast<float2*>(&M[h * 65536 + i * 256 + j0]) = v;
    }
  } else {
#pragma unroll
    for (int r = 0; r < 32; ++r) {
      int o = i0 + ihalf * 32 + r;
      float2 v = make_float2(acc0[r], acc1[r]);
      *reinterpret_cast<float2*>(&Uall[o * 2048 + h * 256 + j0]) = v;
    }
  }
}

// ---------------- u_h = Wk_h^T bq_h / 16 ----------------
__global__ void msa_u(const float* __restrict__ Wk, const float* __restrict__ bq,
                      float* __restrict__ u) {
  __shared__ float bqs[256];
  const int h = blockIdx.x, t = threadIdx.x;
  bqs[t] = bq[h * 256 + t];
  __syncthreads();
  float acc = 0.f;
  for (int dh = 0; dh < 256; ++dh)
    acc = fmaf(Wk[(h * 256 + dh) * 256 + t], bqs[dh], acc);
  u[h * 256 + t] = acc * 0.0625f;
}

// ---------------- b' = bo + Wo bv ----------------
__global__ void msa_bp(const float* __restrict__ Wo, const float* __restrict__ bv,
                       const float* __restrict__ bo, float* __restrict__ bp) {
  const int o = blockIdx.x, t = threadIdx.x;
  float acc = 0.f;
  for (int f = t; f < 2048; f += 256)
    acc = fmaf(Wo[o * 2048 + f], bv[f], acc);
#pragma unroll
  for (int m = 32; m >= 1; m >>= 1) acc += __shfl_down(acc, m);
  __shared__ float part[4];
  if ((t & 63) == 0) part[t >> 6] = acc;
  __syncthreads();
  if (t == 0) bp[o] = bo[o] + part[0] + part[1] + part[2] + part[3];
}

// ---------------- ck[n,h,p] = sum_i X_n[i,p] u_h[i] ----------------
__global__ void msa_ck(const float* __restrict__ X, const float* __restrict__ u,
                       float* __restrict__ ck) {
  __shared__ float us[256];
  const int t = threadIdx.x;
  const int pt = blockIdx.x, h = blockIdx.y, n = blockIdx.z;
  us[t] = u[h * 256 + t];
  __syncthreads();
  const int p = pt * 256 + t;
  const float* __restrict__ Xn = X + n * (DD * PP);
  float acc = 0.f;
  for (int i = 0; i < 256; ++i) acc = fmaf(Xn[i * PP + p], us[i], acc);
  ck[(n * NH + h) * PP + p] = acc;
}

// ---------------- fused T-compute + flash attention ----------------
// grid (16 q-tiles, 8 heads, 8 batch), 512 threads, 148 KiB dynamic LDS
__global__ __launch_bounds__(512, 1) void msa_flash(
    const float* __restrict__ X, const float* __restrict__ pos,
    const float* __restrict__ M, const float* __restrict__ ck,
    float* __restrict__ Y) {
  extern __shared__ float smf[];
  float* Tq = smf + L_TQ;    // [256][64]
  float* Mt = smf + L_TQ;    // [32][260]  (phase A alias)
  float* Xq = smf + L_XQ;    // [256][64]  (phase A)
  float* Xc = smf + L_XQ;    // [64][260]  (phase B alias)
  float* Pl = smf + L_PL;    // [64][64]
  float* cks = smf + L_CK;
  float* red = smf + L_RED;  // [8][64]
  float* mnew = smf + L_MNEW;
  float* scl = smf + L_SCL;
  float* mrun = smf + L_MRUN;
  float* lrun = smf + L_LRUN;

  const int t = threadIdx.x;
  const int qt = blockIdx.x, h = blockIdx.y, n = blockIdx.z;
  const int qg0 = qt * QT;
  const float* __restrict__ Xn = X + n * (DD * PP);

  const int d0 = (t >> 3) * 4;   // 4 output rows (i in T-phase, d in Y-phase)
  const int q0y = (t & 7) * 8;   // 8 output cols
  const int q0s = (t & 15) * 4;  // S-phase: 4 q cols
  const int kk0 = (t >> 4) * 2;  // S-phase: 2 kk rows

  // ---- phase A: Tq = M_h @ Xn[:, q-tile] ----
  for (int s = 0; s < 32; ++s) {
    int f = t + s * 512;
    int j = f >> 6, q = f & 63;
    Xq[f] = Xn[j * PP + qg0 + q];
  }
  float tacc[4][8];
#pragma unroll
  for (int r = 0; r < 4; ++r)
#pragma unroll
    for (int c = 0; c < 8; ++c) tacc[r][c] = 0.f;

  const float* __restrict__ Mh = M + h * (DD * DD);
  for (int jc = 0; jc < DD; jc += 32) {
    __syncthreads();
    for (int s = 0; s < 16; ++s) {
      int f = t + s * 512;
      int i = f >> 5, jj = f & 31;
      Mt[jj * 260 + i] = Mh[i * DD + jc + jj];
    }
    __syncthreads();
#pragma unroll 4
    for (int jj = 0; jj < 32; ++jj) {
      float ma[4], xa[8];
      *reinterpret_cast<float4*>(ma) = *reinterpret_cast<const float4*>(&Mt[jj * 260 + d0]);
      *reinterpret_cast<float4*>(xa) = *reinterpret_cast<const float4*>(&Xq[(jc + jj) * 64 + q0y]);
      *reinterpret_cast<float4*>(xa + 4) = *reinterpret_cast<const float4*>(&Xq[(jc + jj) * 64 + q0y + 4]);
#pragma unroll
      for (int r = 0; r < 4; ++r)
#pragma unroll
        for (int c = 0; c < 8; ++c) tacc[r][c] = fmaf(ma[r], xa[c], tacc[r][c]);
    }
  }
  __syncthreads();
#pragma unroll
  for (int r = 0; r < 4; ++r) {
    *reinterpret_cast<float4*>(&Tq[(d0 + r) * 64 + q0y]) = *reinterpret_cast<float4*>(&tacc[r][0]);
    *reinterpret_cast<float4*>(&Tq[(d0 + r) * 64 + q0y + 4]) = *reinterpret_cast<float4*>(&tacc[r][4]);
  }
  if (t < 64) { mrun[t] = -3.402823466e38f; lrun[t] = 0.f; }

  float yacc[4][8];
#pragma unroll
  for (int r = 0; r < 4; ++r)
#pragma unroll
    for (int c = 0; c < 8; ++c) yacc[r][c] = 0.f;

  const float* __restrict__ posh = pos + h * (PP * PP);
  const float* __restrict__ ckh = ck + (n * NH + h) * PP;

  // ---- phase B: flash loop over k-tiles ----
  for (int kt = 0; kt < PP / KT; ++kt) {
    const int k0 = kt * KT;
    __syncthreads();  // previous tile's Xc/Pl reads complete
    for (int s = 0; s < 32; ++s) {
      int f = t + s * 512;
      int kk = f & 63, i = f >> 6;
      Xc[kk * 260 + i] = Xn[i * PP + k0 + kk];
    }
    if (t < 64) cks[t] = ckh[k0 + t];
    __syncthreads();

    // S[kk0..kk0+1][q0s..q0s+3] = sum_i X[i][k] * Tq[i][q]
    float s0[4] = {0.f, 0.f, 0.f, 0.f}, s1[4] = {0.f, 0.f, 0.f, 0.f};
    {
      const float* __restrict__ x0p = Xc + kk0 * 260;
      const float* __restrict__ x1p = x0p + 260;
#pragma unroll 4
      for (int i = 0; i < DD; ++i) {
        float tv[4];
        *reinterpret_cast<float4*>(tv) = *reinterpret_cast<const float4*>(&Tq[i * 64 + q0s]);
        float x0 = x0p[i], x1 = x1p[i];
#pragma unroll
        for (int c = 0; c < 4; ++c) {
          s0[c] = fmaf(x0, tv[c], s0[c]);
          s1[c] = fmaf(x1, tv[c], s1[c]);
        }
      }
    }
    // + ck[k] + pos[h,k,q]
    {
      const float* pp0 = posh + (k0 + kk0) * PP + qg0 + q0s;
      float pb0[4], pb1[4];
      *reinterpret_cast<float4*>(pb0) = *reinterpret_cast<const float4*>(pp0);
      *reinterpret_cast<float4*>(pb1) = *reinterpret_cast<const float4*>(pp0 + PP);
      float c0 = cks[kk0], c1 = cks[kk0 + 1];
#pragma unroll
      for (int c = 0; c < 4; ++c) { s0[c] += c0 + pb0[c]; s1[c] += c1 + pb1[c]; }
    }
    // tile max over kk (in-wave shfl over the 4 kk-groups, then cross-wave LDS)
    float pm[4];
#pragma unroll
    for (int c = 0; c < 4; ++c) {
      pm[c] = fmaxf(s0[c], s1[c]);
      pm[c] = fmaxf(pm[c], __shfl_xor(pm[c], 16));
      pm[c] = fmaxf(pm[c], __shfl_xor(pm[c], 32));
    }
    if ((t & 63) < 16)
      *reinterpret_cast<float4*>(&red[(t >> 6) * 64 + q0s]) = *reinterpret_cast<float4*>(pm);
    __syncthreads();
    if (t < 64) {
      float mt = red[t];
#pragma unroll
      for (int w = 1; w < 8; ++w) mt = fmaxf(mt, red[w * 64 + t]);
      float mo = mrun[t];
      float mn = fmaxf(mo, mt);
      scl[t] = __expf(mo - mn);
      mnew[t] = mn;
      mrun[t] = mn;
    }
    __syncthreads();
    {
      float mn4[4];
      *reinterpret_cast<float4*>(mn4) = *reinterpret_cast<const float4*>(&mnew[q0s]);
#pragma unroll
      for (int c = 0; c < 4; ++c) {
        s0[c] = __expf(s0[c] - mn4[c]);
        s1[c] = __expf(s1[c] - mn4[c]);
      }
    }
    *reinterpret_cast<float4*>(&Pl[kk0 * 64 + q0s]) = *reinterpret_cast<float4*>(s0);
    *reinterpret_cast<float4*>(&Pl[(kk0 + 1) * 64 + q0s]) = *reinterpret_cast<float4*>(s1);
    float ps[4];
#pragma unroll
    for (int c = 0; c < 4; ++c) {
      ps[c] = s0[c] + s1[c];
      ps[c] += __shfl_xor(ps[c], 16);
      ps[c] += __shfl_xor(ps[c], 32);
    }
    if ((t & 63) < 16)
      *reinterpret_cast<float4*>(&red[(t >> 6) * 64 + q0s]) = *reinterpret_cast<float4*>(ps);
    __syncthreads();
    if (t < 64) {
      float sm_ = red[t];
#pragma unroll
      for (int w = 1; w < 8; ++w) sm_ += red[w * 64 + t];
      lrun[t] = lrun[t] * scl[t] + sm_;
    }
    // rescale Y-accumulator and add X[:,ktile] @ P
    {
      float sc8[8];
      *reinterpret_cast<float4*>(sc8) = *reinterpret_cast<const float4*>(&scl[q0y]);
      *reinterpret_cast<float4*>(sc8 + 4) = *reinterpret_cast<const float4*>(&scl[q0y + 4]);
#pragma unroll
      for (int r = 0; r < 4; ++r)
#pragma unroll
        for (int c = 0; c < 8; ++c) yacc[r][c] *= sc8[c];
    }
#pragma unroll 2
    for (int kk = 0; kk < KT; ++kk) {
      float xa[4], pa[8];
      *reinterpret_cast<float4*>(xa) = *reinterpret_cast<const float4*>(&Xc[kk * 260 + d0]);
      *reinterpret_cast<float4*>(pa) = *reinterpret_cast<const float4*>(&Pl[kk * 64 + q0y]);
      *reinterpret_cast<float4*>(pa + 4) = *reinterpret_cast<const float4*>(&Pl[kk * 64 + q0y + 4]);
#pragma unroll
      for (int r = 0; r < 4; ++r)
#pragma unroll
        for (int c = 0; c < 8; ++c) yacc[r][c] = fmaf(xa[r], pa[c], yacc[r][c]);
    }
  }
  __syncthreads();
  float li[8];
  *reinterpret_cast<float4*>(li) = *reinterpret_cast<const float4*>(&lrun[q0y]);
  *reinterpret_cast<float4*>(li + 4) = *reinterpret_cast<const float4*>(&lrun[q0y + 4]);
#pragma unroll
  for (int c = 0; c < 8; ++c) li[c] = 1.0f / li[c];
  float* Yp = Y + ((size_t)((n * NH + h) * DD + d0)) * PP + qg0 + q0y;
#pragma unroll
  for (int r = 0; r < 4; ++r) {
    float o8[8];
#pragma unroll
    for (int c = 0; c < 8; ++c) o8[c] = yacc[r][c] * li[c];
    *reinterpret_cast<float4*>(Yp + r * PP) = *reinterpret_cast<float4*>(o8);
    *reinterpret_cast<float4*>(Yp + r * PP + 4) = *reinterpret_cast<float4*>(o8 + 4);
  }
}

// ---------------- out_n = U_all @ Y_n + b' ----------------
// grid (8 p-tiles, 4 m-tiles, 8 batch), 256 threads
__global__ __launch_bounds__(256, 1) void msa_final(
    const float* __restrict__ U, const float* __restrict__ Yb,
    const float* __restrict__ bp, float* __restrict__ out) {
  __shared__ float Al[64 * 33];
  __shared__ float Bl[32 * 128];
  const int t = threadIdx.x;
  const int pb0 = blockIdx.x * 128, mb = blockIdx.y * 64, n = blockIdx.z;
  const float* __restrict__ Yn = Yb + (size_t)n * (2048 * PP);
  const int p0 = (t & 31) * 4, m0 = (t >> 5) * 8;
  float acc[8][4];
#pragma unroll
  for (int r = 0; r < 8; ++r) {
    float b = bp[mb + m0 + r];
#pragma unroll
    for (int c = 0; c < 4; ++c) acc[r][c] = b;
  }
  for (int kc = 0; kc < 2048; kc += 32) {
    __syncthreads();
#pragma unroll
    for (int s = 0; s < 8; ++s) {
      int f = t + s * 256;
      int m = f >> 5, j = f & 31;
      Al[m * 33 + j] = U[(mb + m) * 2048 + kc + j];
    }
#pragma unroll
    for (int s = 0; s < 16; ++s) {
      int f = t + s * 256;
      int j = f >> 7, p = f & 127;
      Bl[j * 128 + p] = Yn[(kc + j) * PP + pb0 + p];
    }
    __syncthreads();
#pragma unroll 2
    for (int j = 0; j < 32; ++j) {
      float bv[4];
      *reinterpret_cast<float4*>(bv) = *reinterpret_cast<const float4*>(&Bl[j * 128 + p0]);
#pragma unroll
      for (int r = 0; r < 8; ++r) {
        float a = Al[(m0 + r) * 33 + j];
#pragma unroll
        for (int c = 0; c < 4; ++c) acc[r][c] = fmaf(a, bv[c], acc[r][c]);
      }
    }
  }
#pragma unroll
  for (int r = 0; r < 8; ++r) {
    *reinterpret_cast<float4*>(&out[((size_t)n * DD + (mb + m0 + r)) * PP + pb0 + p0]) =
        *reinterpret_cast<float4*>(&acc[r][0]);
  }
}

extern "C" void kernel_launch(void* const* d_in, const int* in_sizes, int n_in,
                              void* d_out, int out_size, void* d_ws, size_t ws_size,
                              hipStream_t stream) {
  const float* X   = (const float*)d_in[0];
  const float* pos = (const float*)d_in[1];
  const float* Wk  = (const float*)d_in[2];
  // d_in[3] = bk: adds a q-only constant -> cancels in softmax over k. Unused.
  const float* Wq  = (const float*)d_in[4];
  const float* bq  = (const float*)d_in[5];
  const float* Wv  = (const float*)d_in[6];
  const float* bv  = (const float*)d_in[7];
  const float* Wo  = (const float*)d_in[8];
  const float* bo  = (const float*)d_in[9];

  float* ws   = (float*)d_ws;
  float* M    = ws + OFF_M;
  float* Uall = ws + OFF_U;
  float* u    = ws + OFF_u;
  float* bp   = ws + OFF_bp;
  float* ck   = ws + OFF_ck;
  float* Y    = ws + OFF_Y;
  float* out  = (float*)d_out;

  hipFuncSetAttribute(reinterpret_cast<const void*>(msa_flash),
                      hipFuncAttributeMaxDynamicSharedMemorySize, L_TOTAL * 4);

  msa_mu<<<dim3(4, 8, 2), 256, 0, stream>>>(Wk, Wq, Wo, Wv, M, Uall);
  msa_u<<<8, 256, 0, stream>>>(Wk, bq, u);
  msa_bp<<<256, 256, 0, stream>>>(Wo, bv, bo, bp);
  msa_ck<<<dim3(4, 8, 8), 256, 0, stream>>>(X, u, ck);
  msa_flash<<<dim3(16, 8, 8), 512, L_TOTAL * 4, stream>>>(X, pos, M, ck, Y);
  msa_final<<<dim3(8, 4, 8), 256, 0, stream>>>(Uall, Y, bp, out);
}

// Round 2
// 350.299 us; speedup vs baseline: 6.9374x; 6.9374x over previous
//
#include <hip/hip_runtime.h>

typedef __bf16 bf16;
typedef __attribute__((ext_vector_type(8))) __bf16 bf16x8;
typedef __attribute__((ext_vector_type(4))) __bf16 bf16x4;
typedef __attribute__((ext_vector_type(2))) __bf16 bf16x2;
typedef __attribute__((ext_vector_type(4))) float f32x4;

#define MFMA16(a, b, c) __builtin_amdgcn_mfma_f32_16x16x32_bf16(a, b, c, 0, 0, 0)

constexpr int NH = 8, DD = 256, PP = 1024;

// ---- workspace byte offsets ----
constexpr size_t WB_TT  = 0;          // Tt  bf16 [64][1024][256]  (T^T per n,h)
constexpr size_t WB_YT  = 33554432;   // Yt  bf16 [64][1024][256]  (Y^T per n,h)
constexpr size_t WB_XB  = 67108864;   // Xb  bf16 [8][256][1024]
constexpr size_t WB_XBT = 71303168;   // XbT bf16 [8][1024][256]
constexpr size_t WB_MB  = 75497472;   // Mb  bf16 [8][256][256]
constexpr size_t WB_UB  = 76546048;   // Ub  bf16 [256][2048]
constexpr size_t WB_U   = 77594624;   // u   f32  [8][256]
constexpr size_t WB_BP  = 77602816;   // bp  f32  [256]
constexpr size_t WB_CK  = 77603840;   // ck  f32  [64][1024]

// ---- flash LDS layout (bytes) ----
constexpr int FL_TT  = 0;             // Tt tile [64 q][256 i] bf16, swizzled
constexpr int FL_XT  = 32768;         // Xt tile [64 k][256 i] bf16, swizzled
constexpr int FL_PT  = 65536;         // Pt tile [64 q][64 k] bf16, swizzled
constexpr int FL_MR  = 73728;         // mrun[64] f32
constexpr int FL_LR  = 73984;         // lrun[64]
constexpr int FL_MN  = 74240;         // mnew[64]
constexpr int FL_SC  = 74496;         // scl[64]
constexpr int FL_RED = 74752;         // red[4][64] f32
constexpr int FL_SZ  = 75776;

// ---------------- M_h (bf16) and U_h (bf16) precompute ----------------
__global__ __launch_bounds__(256, 1) void msa_mu(
    const float* __restrict__ Wk, const float* __restrict__ Wq,
    const float* __restrict__ Wo, const float* __restrict__ Wv,
    bf16* __restrict__ Mb, bf16* __restrict__ Ub) {
  __shared__ float lds[64 * 65];
  const int t = threadIdx.x;
  const int i0 = blockIdx.x * 64;
  const int h = blockIdx.y;
  const int mode = blockIdx.z;
  const int j0 = (t & 127) * 2;
  const int ihalf = t >> 7;
  float acc0[32], acc1[32];
#pragma unroll
  for (int r = 0; r < 32; ++r) { acc0[r] = 0.f; acc1[r] = 0.f; }
  const float* __restrict__ W2 = (mode == 0) ? Wq : Wv;
  for (int dhc = 0; dhc < 256; dhc += 64) {
    __syncthreads();
    if (mode == 0) {
#pragma unroll
      for (int s = 0; s < 16; ++s) {
        int f = t + s * 256;
        int dh = f >> 6, ii = f & 63;
        lds[dh * 65 + ii] = Wk[(h * 256 + dhc + dh) * 256 + i0 + ii];
      }
    } else {
#pragma unroll
      for (int s = 0; s < 16; ++s) {
        int f = t + s * 256;
        int oo = f >> 6, dh = f & 63;
        lds[dh * 65 + oo] = Wo[(i0 + oo) * 2048 + h * 256 + dhc + dh];
      }
    }
    __syncthreads();
    for (int dl = 0; dl < 64; ++dl) {
      float2 w = *reinterpret_cast<const float2*>(&W2[(h * 256 + dhc + dl) * 256 + j0]);
#pragma unroll
      for (int r = 0; r < 32; ++r) {
        float x = lds[dl * 65 + ihalf * 32 + r];
        acc0[r] = fmaf(x, w.x, acc0[r]);
        acc1[r] = fmaf(x, w.y, acc1[r]);
      }
    }
  }
  if (mode == 0) {
#pragma unroll
    for (int r = 0; r < 32; ++r) {
      int i = i0 + ihalf * 32 + r;
      bf16x2 v = { (__bf16)(acc0[r] * 0.0625f), (__bf16)(acc1[r] * 0.0625f) };
      *reinterpret_cast<bf16x2*>(&Mb[h * 65536 + i * 256 + j0]) = v;
    }
  } else {
#pragma unroll
    for (int r = 0; r < 32; ++r) {
      int o = i0 + ihalf * 32 + r;
      bf16x2 v = { (__bf16)acc0[r], (__bf16)acc1[r] };
      *reinterpret_cast<bf16x2*>(&Ub[o * 2048 + h * 256 + j0]) = v;
    }
  }
}

// ---------------- u_h = Wk_h^T bq_h / 16 ----------------
__global__ void msa_u(const float* __restrict__ Wk, const float* __restrict__ bq,
                      float* __restrict__ u) {
  __shared__ float bqs[256];
  const int h = blockIdx.x, t = threadIdx.x;
  bqs[t] = bq[h * 256 + t];
  __syncthreads();
  float acc = 0.f;
  for (int dh = 0; dh < 256; ++dh)
    acc = fmaf(Wk[(h * 256 + dh) * 256 + t], bqs[dh], acc);
  u[h * 256 + t] = acc * 0.0625f;
}

// ---------------- b' = bo + Wo bv ----------------
__global__ void msa_bp(const float* __restrict__ Wo, const float* __restrict__ bv,
                       const float* __restrict__ bo, float* __restrict__ bp) {
  const int o = blockIdx.x, t = threadIdx.x;
  float acc = 0.f;
  for (int f = t; f < 2048; f += 256)
    acc = fmaf(Wo[o * 2048 + f], bv[f], acc);
#pragma unroll
  for (int m = 32; m >= 1; m >>= 1) acc += __shfl_down(acc, m);
  __shared__ float part[4];
  if ((t & 63) == 0) part[t >> 6] = acc;
  __syncthreads();
  if (t == 0) bp[o] = bo[o] + part[0] + part[1] + part[2] + part[3];
}

// ---------------- ck[n,h,p] = sum_i X_n[i,p] u_h[i] ----------------
__global__ void msa_ck(const float* __restrict__ X, const float* __restrict__ u,
                       float* __restrict__ ck) {
  __shared__ float us[256];
  const int t = threadIdx.x;
  const int pt = blockIdx.x, h = blockIdx.y, n = blockIdx.z;
  us[t] = u[h * 256 + t];
  __syncthreads();
  const int p = pt * 256 + t;
  const float* __restrict__ Xn = X + (size_t)n * (DD * PP);
  float acc = 0.f;
  for (int i = 0; i < 256; ++i) acc = fmaf(Xn[i * PP + p], us[i], acc);
  ck[(n * NH + h) * PP + p] = acc;
}

// ---------------- X -> bf16 in both layouts ----------------
// grid (16 ptile, 4 dtile, 8 n), 256 threads
__global__ __launch_bounds__(256, 4) void msa_cvtX(
    const float* __restrict__ X, bf16* __restrict__ Xb, bf16* __restrict__ XbT) {
  __shared__ __bf16 tl[64 * 68];
  const int t = threadIdx.x;
  const int p0 = blockIdx.x * 64, d0 = blockIdx.y * 64, n = blockIdx.z;
  const float* __restrict__ Xn = X + (size_t)n * DD * PP;
#pragma unroll
  for (int rr = 0; rr < 4; ++rr) {
    int r = (t >> 4) + rr * 16, c = (t & 15) * 4;
    float4 v = *reinterpret_cast<const float4*>(Xn + (size_t)(d0 + r) * PP + p0 + c);
    bf16x4 pk = { (__bf16)v.x, (__bf16)v.y, (__bf16)v.z, (__bf16)v.w };
    *reinterpret_cast<bf16x4*>(Xb + (size_t)n * DD * PP + (size_t)(d0 + r) * PP + p0 + c) = pk;
    *reinterpret_cast<bf16x4*>(&tl[r * 68 + c]) = pk;
  }
  __syncthreads();
#pragma unroll
  for (int rr = 0; rr < 4; ++rr) {
    int pr = (t >> 4) + rr * 16, dc = (t & 15) * 4;
    bf16x4 pk = { tl[(dc + 0) * 68 + pr], tl[(dc + 1) * 68 + pr],
                  tl[(dc + 2) * 68 + pr], tl[(dc + 3) * 68 + pr] };
    *reinterpret_cast<bf16x4*>(XbT + (size_t)n * PP * DD + (size_t)(p0 + pr) * DD + d0 + dc) = pk;
  }
}

// ---------------- Tt[n,h][q][i] = (M_h @ X_n)^T, bf16 MFMA ----------------
// grid (8 qb, 2 ib, 64 nh), 256 threads
__global__ __launch_bounds__(256, 2) void msa_T(
    const bf16* __restrict__ XbT, const bf16* __restrict__ Mb, bf16* __restrict__ Ttg) {
  const int t = threadIdx.x, lane = t & 63, w = t >> 6;
  const int g = lane >> 4, ln = lane & 15;
  const int qw2 = w >> 1, iw = w & 1;
  const int qb = blockIdx.x, ib2 = blockIdx.y, nh = blockIdx.z;
  const int n = nh >> 3, h = nh & 7;
  const bf16* __restrict__ Xq = XbT + (size_t)n * (PP * DD) + (size_t)(qb * 128 + qw2 * 64) * DD;
  const bf16* __restrict__ Mh = Mb + (size_t)h * (DD * DD) + (size_t)(ib2 * 128 + iw * 64) * DD;
  f32x4 acc[4][4];
#pragma unroll
  for (int a = 0; a < 4; ++a)
#pragma unroll
    for (int b = 0; b < 4; ++b) { f32x4 z = {0.f, 0.f, 0.f, 0.f}; acc[a][b] = z; }
#pragma unroll
  for (int s = 0; s < 8; ++s) {
    bf16x8 a[4], b[4];
#pragma unroll
    for (int mq = 0; mq < 4; ++mq)
      a[mq] = *reinterpret_cast<const bf16x8*>(Xq + (size_t)(mq * 16 + ln) * DD + s * 32 + g * 8);
#pragma unroll
    for (int ni = 0; ni < 4; ++ni)
      b[ni] = *reinterpret_cast<const bf16x8*>(Mh + (size_t)(ni * 16 + ln) * DD + s * 32 + g * 8);
#pragma unroll
    for (int mq = 0; mq < 4; ++mq)
#pragma unroll
      for (int ni = 0; ni < 4; ++ni) acc[mq][ni] = MFMA16(a[mq], b[ni], acc[mq][ni]);
  }
  bf16* __restrict__ outp = Ttg + (size_t)nh * (PP * DD);
#pragma unroll
  for (int mq = 0; mq < 4; ++mq)
#pragma unroll
    for (int ni = 0; ni < 4; ++ni)
#pragma unroll
      for (int r = 0; r < 4; ++r)
        outp[(size_t)(qb * 128 + qw2 * 64 + mq * 16 + 4 * g + r) * DD +
             ib2 * 128 + iw * 64 + ni * 16 + ln] = (__bf16)acc[mq][ni][r];
}

// ---------------- fused flash attention, bf16 MFMA ----------------
// grid (16 qt, 8 h, 8 n), 256 threads (4 waves), FL_SZ dynamic LDS
__global__ __launch_bounds__(256, 2) void msa_flash(
    const bf16* __restrict__ XbT, const bf16* __restrict__ Xb,
    const bf16* __restrict__ Ttg, const float* __restrict__ pos,
    const float* __restrict__ ck, bf16* __restrict__ Yt) {
  extern __shared__ char smc[];
  const int t = threadIdx.x;
  const int lane = t & 63, w = t >> 6;
  const int g = lane >> 4, ln = lane & 15;
  const int kw = w >> 1, qw = w & 1;
  const int qt = blockIdx.x, h = blockIdx.y, n = blockIdx.z;
  const int qg0 = qt * 64, nh = n * 8 + h;
  const bf16* __restrict__ XbTn = XbT + (size_t)n * (PP * DD);
  const bf16* __restrict__ Xbn  = Xb + (size_t)n * (DD * PP);
  const bf16* __restrict__ Tth  = Ttg + (size_t)nh * (PP * DD);
  const float* __restrict__ posh = pos + (size_t)h * (PP * PP);
  const float* __restrict__ ckh = ck + nh * PP;
  float* mrun = (float*)(smc + FL_MR);
  float* lrun = (float*)(smc + FL_LR);
  float* mnew = (float*)(smc + FL_MN);
  float* scl  = (float*)(smc + FL_SC);
  float* red  = (float*)(smc + FL_RED);

  // stage Tt tile [64 q][256 i], XOR-swizzled rows
#pragma unroll
  for (int m = 0; m < 8; ++m) {
    int f = t + m * 256, row = f >> 5, c = f & 31;
    uint4 v = *reinterpret_cast<const uint4*>(Tth + (size_t)(qg0 + row) * DD + c * 8);
    int b = (row * 512 + c * 16) ^ ((row & 7) << 4);
    *reinterpret_cast<uint4*>(smc + FL_TT + b) = v;
  }
  if (t < 64) { mrun[t] = -3.402823466e38f; lrun[t] = 0.f; }

  f32x4 yacc[4][4];
#pragma unroll
  for (int a = 0; a < 4; ++a)
#pragma unroll
    for (int b = 0; b < 4; ++b) { f32x4 z = {0.f, 0.f, 0.f, 0.f}; yacc[a][b] = z; }

  for (int kt = 0; kt < 16; ++kt) {
    const int kg0 = kt * 64;
    // stage Xt tile [64 k][256 i]
#pragma unroll
    for (int m = 0; m < 8; ++m) {
      int f = t + m * 256, row = f >> 5, c = f & 31;
      uint4 v = *reinterpret_cast<const uint4*>(XbTn + (size_t)(kg0 + row) * DD + c * 8);
      int b = (row * 512 + c * 16) ^ ((row & 7) << 4);
      *reinterpret_cast<uint4*>(smc + FL_XT + b) = v;
    }
    __syncthreads();

    // S = Xt^T-contract-Tt : D[m=k][n=q], wave covers 32k x 32q
    f32x4 sacc[2][2];
#pragma unroll
    for (int a = 0; a < 2; ++a)
#pragma unroll
      for (int b = 0; b < 2; ++b) { f32x4 z = {0.f, 0.f, 0.f, 0.f}; sacc[a][b] = z; }
#pragma unroll
    for (int s = 0; s < 8; ++s) {
      const int ib = s * 64 + g * 16;
      const int ra = kw * 32 + ln, rb = ra + 16;
      const int ca = qw * 32 + ln, cb = ca + 16;
      bf16x8 a0 = *reinterpret_cast<const bf16x8*>(smc + FL_XT + ((ra * 512 + ib) ^ ((ra & 7) << 4)));
      bf16x8 a1 = *reinterpret_cast<const bf16x8*>(smc + FL_XT + ((rb * 512 + ib) ^ ((rb & 7) << 4)));
      bf16x8 b0 = *reinterpret_cast<const bf16x8*>(smc + FL_TT + ((ca * 512 + ib) ^ ((ca & 7) << 4)));
      bf16x8 b1 = *reinterpret_cast<const bf16x8*>(smc + FL_TT + ((cb * 512 + ib) ^ ((cb & 7) << 4)));
      sacc[0][0] = MFMA16(a0, b0, sacc[0][0]);
      sacc[0][1] = MFMA16(a0, b1, sacc[0][1]);
      sacc[1][0] = MFMA16(a1, b0, sacc[1][0]);
      sacc[1][1] = MFMA16(a1, b1, sacc[1][1]);
    }

    // + ck[k] + pos[h,k,q]; per-lane max over this wave's k
    float pm0 = -3.402823466e38f, pm1 = -3.402823466e38f;
#pragma unroll
    for (int km = 0; km < 2; ++km)
#pragma unroll
      for (int r = 0; r < 4; ++r) {
        int kl = kw * 32 + km * 16 + 4 * g + r;
        float ckv = ckh[kg0 + kl];
        const float* pr = posh + (size_t)(kg0 + kl) * PP + qg0 + qw * 32 + ln;
        float v0 = sacc[km][0][r] + ckv + pr[0];
        float v1 = sacc[km][1][r] + ckv + pr[16];
        sacc[km][0][r] = v0; sacc[km][1][r] = v1;
        pm0 = fmaxf(pm0, v0); pm1 = fmaxf(pm1, v1);
      }
    pm0 = fmaxf(pm0, __shfl_xor(pm0, 16)); pm0 = fmaxf(pm0, __shfl_xor(pm0, 32));
    pm1 = fmaxf(pm1, __shfl_xor(pm1, 16)); pm1 = fmaxf(pm1, __shfl_xor(pm1, 32));
    if (lane < 16) {
      red[w * 64 + qw * 32 + ln] = pm0;
      red[w * 64 + qw * 32 + 16 + ln] = pm1;
    }
    __syncthreads();
    if (t < 64) {
      int rA = (t >> 5) & 1;
      float mt = fmaxf(red[rA * 64 + t], red[(rA + 2) * 64 + t]);
      float mo = mrun[t], mn = fmaxf(mo, mt);
      scl[t] = __expf(mo - mn);
      mnew[t] = mn; mrun[t] = mn;
    }
    __syncthreads();

    // P = exp(S - mnew): pack bf16 into swizzled Pt[q][k]; partial sums
    float mq0 = mnew[qw * 32 + ln], mq1 = mnew[qw * 32 + 16 + ln];
    float ps0 = 0.f, ps1 = 0.f;
#pragma unroll
    for (int km = 0; km < 2; ++km) {
      bf16x4 pk0, pk1;
#pragma unroll
      for (int r = 0; r < 4; ++r) {
        float e0 = __expf(sacc[km][0][r] - mq0); ps0 += e0; pk0[r] = (__bf16)e0;
        float e1 = __expf(sacc[km][1][r] - mq1); ps1 += e1; pk1[r] = (__bf16)e1;
      }
      int kl2 = (kw * 32 + km * 16 + 4 * g) * 2;
      int q0b = qw * 32 + ln, q1b = q0b + 16;
      *reinterpret_cast<bf16x4*>(smc + FL_PT + ((q0b * 128 + kl2) ^ ((q0b & 7) << 4))) = pk0;
      *reinterpret_cast<bf16x4*>(smc + FL_PT + ((q1b * 128 + kl2) ^ ((q1b & 7) << 4))) = pk1;
    }
    ps0 += __shfl_xor(ps0, 16); ps0 += __shfl_xor(ps0, 32);
    ps1 += __shfl_xor(ps1, 16); ps1 += __shfl_xor(ps1, 32);
    if (lane < 16) {
      red[w * 64 + qw * 32 + ln] = ps0;
      red[w * 64 + qw * 32 + 16 + ln] = ps1;
    }
    __syncthreads();
    if (t < 64) {
      int rA = (t >> 5) & 1;
      float sm_ = red[rA * 64 + t] + red[(rA + 2) * 64 + t];
      lrun[t] = lrun[t] * scl[t] + sm_;
    }
    __syncthreads();

    // PV: Yt[q][d] += Pt[q][:] * Xb[d][:]; wave owns d-block w*64
    f32x4 sc4[4];
#pragma unroll
    for (int mq = 0; mq < 4; ++mq)
      sc4[mq] = *reinterpret_cast<const f32x4*>(scl + mq * 16 + 4 * g);
#pragma unroll
    for (int mq = 0; mq < 4; ++mq)
#pragma unroll
      for (int nd = 0; nd < 4; ++nd)
#pragma unroll
        for (int r = 0; r < 4; ++r) yacc[mq][nd][r] *= sc4[mq][r];
#pragma unroll
    for (int ks = 0; ks < 2; ++ks) {
      bf16x8 pa[4], xv[4];
#pragma unroll
      for (int mq = 0; mq < 4; ++mq) {
        int q = mq * 16 + ln;
        pa[mq] = *reinterpret_cast<const bf16x8*>(
            smc + FL_PT + ((q * 128 + ks * 64 + g * 16) ^ ((q & 7) << 4)));
      }
#pragma unroll
      for (int nd = 0; nd < 4; ++nd)
        xv[nd] = *reinterpret_cast<const bf16x8*>(
            Xbn + (size_t)(w * 64 + nd * 16 + ln) * PP + kg0 + ks * 32 + g * 8);
#pragma unroll
      for (int mq = 0; mq < 4; ++mq)
#pragma unroll
        for (int nd = 0; nd < 4; ++nd)
          yacc[mq][nd] = MFMA16(pa[mq], xv[nd], yacc[mq][nd]);
    }
  }

  // epilogue: Yt[n,h][q][d] = yacc / lrun[q], bf16
  bf16* __restrict__ Ytp = Yt + (size_t)nh * (PP * DD);
#pragma unroll
  for (int mq = 0; mq < 4; ++mq) {
    f32x4 lv = *reinterpret_cast<const f32x4*>(lrun + mq * 16 + 4 * g);
    f32x4 inv;
#pragma unroll
    for (int r = 0; r < 4; ++r) inv[r] = 1.0f / lv[r];
#pragma unroll
    for (int nd = 0; nd < 4; ++nd)
#pragma unroll
      for (int r = 0; r < 4; ++r)
        Ytp[(size_t)(qg0 + mq * 16 + 4 * g + r) * DD + w * 64 + nd * 16 + ln] =
            (__bf16)(yacc[mq][nd][r] * inv[r]);
  }
}

// ---------------- out = Ub @ Y + b', bf16 MFMA ----------------
// grid (8 pb, 4 ob, 8 n), 256 threads
__global__ __launch_bounds__(256, 2) void msa_final2(
    const bf16* __restrict__ Ub, const bf16* __restrict__ Yt,
    const float* __restrict__ bp, float* __restrict__ out) {
  const int t = threadIdx.x, lane = t & 63, w = t >> 6;
  const int g = lane >> 4, ln = lane & 15;
  const int pb = blockIdx.x, ob = blockIdx.y, n = blockIdx.z;
  f32x4 acc[4][2];
#pragma unroll
  for (int a = 0; a < 4; ++a)
#pragma unroll
    for (int b = 0; b < 2; ++b) { f32x4 z = {0.f, 0.f, 0.f, 0.f}; acc[a][b] = z; }
  for (int js = 0; js < 64; ++js) {
    int f0 = js * 32, hh = f0 >> 8, d0 = f0 & 255;
    bf16x8 a[4], b[2];
#pragma unroll
    for (int mo = 0; mo < 4; ++mo)
      a[mo] = *reinterpret_cast<const bf16x8*>(Ub + (size_t)(ob * 64 + mo * 16 + ln) * 2048 + f0 + g * 8);
#pragma unroll
    for (int np = 0; np < 2; ++np)
      b[np] = *reinterpret_cast<const bf16x8*>(
          Yt + ((size_t)(n * 8 + hh) * PP + pb * 128 + w * 32 + np * 16 + ln) * DD + d0 + g * 8);
#pragma unroll
    for (int mo = 0; mo < 4; ++mo)
#pragma unroll
      for (int np = 0; np < 2; ++np) acc[mo][np] = MFMA16(a[mo], b[np], acc[mo][np]);
  }
#pragma unroll
  for (int mo = 0; mo < 4; ++mo)
#pragma unroll
    for (int np = 0; np < 2; ++np)
#pragma unroll
      for (int r = 0; r < 4; ++r) {
        int o = ob * 64 + mo * 16 + 4 * g + r;
        out[((size_t)n * DD + o) * PP + pb * 128 + w * 32 + np * 16 + ln] =
            acc[mo][np][r] + bp[o];
      }
}

extern "C" void kernel_launch(void* const* d_in, const int* in_sizes, int n_in,
                              void* d_out, int out_size, void* d_ws, size_t ws_size,
                              hipStream_t stream) {
  const float* X   = (const float*)d_in[0];
  const float* pos = (const float*)d_in[1];
  const float* Wk  = (const float*)d_in[2];
  // d_in[3] = bk: q-only constant, cancels in softmax over k. Unused.
  const float* Wq  = (const float*)d_in[4];
  const float* bq  = (const float*)d_in[5];
  const float* Wv  = (const float*)d_in[6];
  const float* bv  = (const float*)d_in[7];
  const float* Wo  = (const float*)d_in[8];
  const float* bo  = (const float*)d_in[9];

  char* ws = (char*)d_ws;
  bf16* Tt  = (bf16*)(ws + WB_TT);
  bf16* Yt  = (bf16*)(ws + WB_YT);
  bf16* Xb  = (bf16*)(ws + WB_XB);
  bf16* XbT = (bf16*)(ws + WB_XBT);
  bf16* Mb  = (bf16*)(ws + WB_MB);
  bf16* Ub  = (bf16*)(ws + WB_UB);
  float* u  = (float*)(ws + WB_U);
  float* bp = (float*)(ws + WB_BP);
  float* ck = (float*)(ws + WB_CK);
  float* out = (float*)d_out;

  hipFuncSetAttribute(reinterpret_cast<const void*>(msa_flash),
                      hipFuncAttributeMaxDynamicSharedMemorySize, FL_SZ);

  msa_cvtX<<<dim3(16, 4, 8), 256, 0, stream>>>(X, Xb, XbT);
  msa_mu<<<dim3(4, 8, 2), 256, 0, stream>>>(Wk, Wq, Wo, Wv, Mb, Ub);
  msa_u<<<8, 256, 0, stream>>>(Wk, bq, u);
  msa_bp<<<256, 256, 0, stream>>>(Wo, bv, bo, bp);
  msa_ck<<<dim3(4, 8, 8), 256, 0, stream>>>(X, u, ck);
  msa_T<<<dim3(8, 2, 64), 256, 0, stream>>>(XbT, Mb, Tt);
  msa_flash<<<dim3(16, 8, 8), 256, FL_SZ, stream>>>(XbT, Xb, Tt, pos, ck, Yt);
  msa_final2<<<dim3(8, 4, 8), 256, 0, stream>>>(Ub, Yt, bp, out);
}